// Round 17
// baseline (191.566 us; speedup 1.0000x reference)
//
#include <hip/hip_runtime.h>
#include <stdint.h>

#define N_TOK 2048
#define C_DIM 1024
#define H_DIM 2048
#define NE 8
#define NSLOT 3

#define BM 128
#define BN 128
#define BK 64
#define PGRID 1024
#define PGRID_UP 768   // GEMM blocks in up (3/CU); +256 cast blocks = 4/CU mixed

// ws layout (bytes)
#define WS_COUNTS   0
#define WS_PLAN     256
#define WS_CW       (WS_PLAN + 1024)
#define WS_ROUTE    (WS_CW + N_TOK*NE*4)
#define WS_LISTS    (WS_ROUTE + N_TOK*4)
#define WS_XB       (WS_LISTS + NE*N_TOK*4)
#define WS_HBUF     (WS_XB + (size_t)N_TOK*C_DIM*2)
#define WS_OUTSLOT  (WS_HBUF + (size_t)N_TOK*NSLOT*H_DIM*2)
#define WS_WT1T     (WS_OUTSLOT + (size_t)N_TOK*NSLOT*C_DIM*2)
#define WS_WT3T     (WS_WT1T + (size_t)NE*H_DIM*C_DIM*2)
#define WS_WT2T     (WS_WT3T + (size_t)NE*H_DIM*C_DIM*2)

typedef short bf16x8 __attribute__((ext_vector_type(8)));
typedef float f32x4 __attribute__((ext_vector_type(4)));

union FragU { bf16x8 v; uint2 u2[2]; };

__device__ __forceinline__ unsigned short f2b(float f) {
    union { float f; uint32_t u; } v; v.f = f;
    return (unsigned short)((v.u + 0x7fffu + ((v.u >> 16) & 1u)) >> 16); // RNE
}
__device__ __forceinline__ float b2f(unsigned short s) {
    union { uint32_t u; float f; } v; v.u = ((uint32_t)s) << 16; return v.f;
}

// async global->LDS, 16B per lane; lds dest is wave-uniform base + lane*16
__device__ __forceinline__ void gload16(const unsigned short* g, unsigned short* l) {
    __builtin_amdgcn_global_load_lds(
        (const __attribute__((address_space(1))) unsigned int*)g,
        (__attribute__((address_space(3))) unsigned int*)l, 16, 0, 0);
}

// ---- tcast v5: 64k x 128n fp32 -> 4 tiles [32 n][64 k] bf16 (16.9KB LDS).
__device__ __forceinline__ void tcast128(
        const float* __restrict__ src, unsigned short* __restrict__ dtile0,
        int N, int NKT, int kt, int nBase, char* lb, int t) {
    uint32_t* L = (uint32_t*)lb;                 // [64][66] u32 = 16896 B
    const int l = t & 63, w = t >> 6;
    const int half = l >> 5, ll = l & 31;
    const float* s = src + (size_t)(kt * 64) * N + nBase;
#pragma unroll 4
    for (int i = 0; i < 8; i++) {
        int k = w * 16 + i * 2 + half;
        float4 v = *(const float4*)(s + (size_t)k * N + 4 * ll);
        uint2 p;
        p.x = (uint32_t)f2b(v.x) | ((uint32_t)f2b(v.y) << 16);   // n=4ll,4ll+1
        p.y = (uint32_t)f2b(v.z) | ((uint32_t)f2b(v.w) << 16);   // n=4ll+2,4ll+3
        *(uint2*)(L + k * 66 + 2 * ll) = p;
    }
    __syncthreads();
    const int rn = t >> 3, cc = t & 7;
#pragma unroll
    for (int s2 = 0; s2 < 4; s2++) {
        int n = s2 * 32 + rn;
        int np = n >> 1, hi = (n & 1) * 16;
        uint32_t o[4];
#pragma unroll
        for (int u = 0; u < 4; u++) {            // out u32 u = k {cc*8+2u, +1}
            uint32_t a = L[(cc * 8 + 2 * u) * 66 + np];
            uint32_t b = L[(cc * 8 + 2 * u + 1) * 66 + np];
            o[u] = ((a >> hi) & 0xffffu) | (((b >> hi) & 0xffffu) << 16);
        }
        unsigned short* drow = dtile0 + (size_t)s2 * NKT * 2048 + rn * 64 + cc * 8;
        *(uint4*)drow = *(uint4*)o;
    }
}

// ---- prepass: gate (blocks 0..511, NO atomics) + w1/w3 tcast (512..4607) ----
__global__ __launch_bounds__(256) void prep_kernel(
        const float* __restrict__ x, const float* __restrict__ gw,
        const float* __restrict__ gb, const float* __restrict__ w1,
        const float* __restrict__ w3, float* __restrict__ cw,
        unsigned short* __restrict__ xb, int* __restrict__ route,
        unsigned short* __restrict__ wt1t, unsigned short* __restrict__ wt3t) {
    __shared__ __align__(16) char smem[16896];
    const int b = blockIdx.x;
    if (b >= 512) {                         // w1/w3 -> wt1t/wt3t (128-n granule)
        int bb = b - 512;
        int op = bb >> 11, r2 = bb & 2047;
        int e = r2 >> 8, rem = r2 & 255, kt = rem >> 4, nB = rem & 15;
        const float* src = (op ? w3 : w1) + (size_t)e * C_DIM * H_DIM;
        unsigned short* dst = (op ? wt3t : wt1t) +
                              ((size_t)(e * 64 + nB * 4) * 16 + kt) * 2048;
        tcast128(src, dst, H_DIM, 16, kt, nB * 128, smem, threadIdx.x);
        return;
    }
    // ---- gate: one wave per token; atomic-free ----
    int n = (b * 256 + threadIdx.x) >> 6;
    int lane = threadIdx.x & 63;
    float acc[NE];
#pragma unroll
    for (int e = 0; e < NE; e++) acc[e] = 0.f;
    for (int c = lane; c < C_DIM; c += 64) {
        float xv = x[n * C_DIM + c];
        xb[n * C_DIM + c] = f2b(xv);
        const float* g = gw + c * NE;
#pragma unroll
        for (int e = 0; e < NE; e++) acc[e] += xv * g[e];
    }
#pragma unroll
    for (int e = 0; e < NE; e++) {
#pragma unroll
        for (int off = 32; off >= 1; off >>= 1) acc[e] += __shfl_xor(acc[e], off, 64);
        acc[e] += gb[e];
    }
    float m = acc[0];
#pragma unroll
    for (int e = 1; e < NE; e++) m = fmaxf(m, acc[e]);
    float s = 0.f, sc[NE];
#pragma unroll
    for (int e = 0; e < NE; e++) { sc[e] = __expf(acc[e] - m); s += sc[e]; }
    float inv = 1.f / s;
#pragma unroll
    for (int e = 0; e < NE; e++) sc[e] *= inv;
    // top-2 of routed experts 1..7; ties -> lower index (matches lax.top_k)
    int i1 = 1; float v1 = sc[1];
#pragma unroll
    for (int e = 2; e < NE; e++) if (sc[e] > v1) { v1 = sc[e]; i1 = e; }
    int i2 = 0; float v2 = -1.f;
#pragma unroll
    for (int e = 1; e < NE; e++) if (e != i1 && sc[e] > v2) { v2 = sc[e]; i2 = e; }
    if (lane < NE) {
        float v = 0.f;
        if (lane == 0) v = sc[0];
        else if (lane == i1) v = v1;
        else if (lane == i2) v = v2;
        cw[n * NE + lane] = v;
    }
    if (lane == 0) route[n] = i1 | (i2 << 8);
}

// ---- lists: 8 blocks (1 wave each), ballot stream-compaction per expert.
__global__ void lists_kernel(const int* __restrict__ route, int* __restrict__ counts,
                             int* __restrict__ lists) {
    const int e = blockIdx.x, lane = threadIdx.x;
    if (e == 0) {                             // shared expert: all tokens, slot 0
        for (int base = 0; base < N_TOK; base += 64)
            lists[base + lane] = (base + lane) * 4;
        if (lane == 0) counts[0] = N_TOK;
        return;
    }
    int cnt = 0;
    for (int base = 0; base < N_TOK; base += 64) {
        int r = route[base + lane];
        int i1 = r & 255, i2 = (r >> 8) & 255;
        bool mt = (i1 == e) || (i2 == e);
        int slot = (i1 == e) ? 1 : 2;
        unsigned long long mask = __ballot(mt);
        int pos = __popcll(mask & ((1ull << lane) - 1ull));
        if (mt) lists[e * N_TOK + cnt + pos] = (base + lane) * 4 + slot;
        cnt += __popcll(mask);
    }
    if (lane == 0) counts[e] = cnt;
}

// ---------------- plan: compacted (expert, m-block) work list ----------------
__global__ void plan_kernel(const int* __restrict__ counts, int* __restrict__ plan) {
    if (threadIdx.x == 0) {
        int p = 0;
        for (int e = 0; e < NE; e++) {
            int nb = (counts[e] + BM - 1) / BM;
            for (int m = 0; m < nb; m++) plan[1 + p++] = (e << 8) | m;
        }
        plan[0] = p;
    }
}

// STAGE: NA A-chunks + NB B-chunks per lane (async 16B global->LDS)
#define STAGE(NA, NB, aoff, boff) do {                                    \
    _Pragma("unroll")                                                     \
    for (int i_ = 0; i_ < (NA); i_++)                                     \
        gload16(asrc[i_] + (aoff), As + (i_ * 256 + t) * 8);              \
    _Pragma("unroll")                                                     \
    for (int i_ = 0; i_ < (NB); i_++)                                     \
        gload16(bsrc[i_] + (boff), Bs + (i_ * 256 + t) * 8);              \
} while (0)

// COMPUTE: ds_read_b128 + MFMA on one 128xN x64 tile; NT = B frags per wave
#define COMPUTE(NT, BEXPR) do {                                           \
    __builtin_amdgcn_s_setprio(1);                                        \
    _Pragma("unroll")                                                     \
    for (int j_ = 0; j_ < 2; j_++) {                                      \
        FragU af[4], bf[NT];                                              \
        _Pragma("unroll")                                                 \
        for (int mt = 0; mt < 4; mt++) {                                  \
            int row = wr * 64 + mt * 16 + ln15;                           \
            int slot = (j_ * 4 + lg) ^ swz;                               \
            af[mt].v = *(const bf16x8*)(As + row * BK + slot * 8);        \
        }                                                                 \
        _Pragma("unroll")                                                 \
        for (int nt = 0; nt < (NT); nt++) {                               \
            int row = (BEXPR);                                            \
            int slot = (j_ * 4 + lg) ^ swz;                               \
            bf[nt].v = *(const bf16x8*)(Bs + row * BK + slot * 8);        \
        }                                                                 \
        _Pragma("unroll")                                                 \
        for (int mt = 0; mt < 4; mt++)                                    \
            _Pragma("unroll")                                             \
            for (int nt = 0; nt < (NT); nt++)                             \
                acc[mt][nt] = __builtin_amdgcn_mfma_f32_16x16x32_bf16(    \
                    af[mt].v, bf[nt].v, acc[mt][nt], 0, 0, 0);            \
    }                                                                     \
    __builtin_amdgcn_s_setprio(0);                                        \
} while (0)

// single-buffer K-loop: staging-BW-bound regime -> serial loop, TLP hides latency
#define KLOOP(NK, NA, NB, NT, BEXPR) do {                                 \
    for (int kt = 0; kt < (NK); kt++) {                                   \
        STAGE(NA, NB, kt * BK, kt * 2048);                                \
        asm volatile("s_waitcnt vmcnt(0)" ::: "memory");                  \
        __builtin_amdgcn_s_barrier();                                     \
        COMPUTE(NT, BEXPR);                                               \
        __builtin_amdgcn_s_barrier();                                     \
    }                                                                     \
} while (0)

// -------- expert up: blocks 0..767 = 128x128 GEMM (3/CU); blocks 768..1023 =
// w2 tcast (8 tiles each, ~25us) running CONCURRENTLY in the GEMM's BW shadow.
// (R7's interleave failed because cast blocks retired early with no backfill;
// here the static 3+1 split keeps 4 blocks/CU and duration-matched phases.)
__global__ __launch_bounds__(256, 4) void expert_up_kernel(
        const unsigned short* __restrict__ xb, const unsigned short* __restrict__ wt1t,
        const unsigned short* __restrict__ wt3t, const float* __restrict__ b1,
        const float* __restrict__ b3, const int* __restrict__ counts,
        const int* __restrict__ lists, const int* __restrict__ plan,
        unsigned short* __restrict__ hbuf, const float* __restrict__ w2,
        unsigned short* __restrict__ wt2t) {
    const int t = threadIdx.x;
    __shared__ __align__(16) char smem[33792];

    if (blockIdx.x >= PGRID_UP) {   // ---- w2 cast: 8 tcast128 tiles per block ----
        int cb = blockIdx.x - PGRID_UP;
#pragma unroll 1
        for (int i = 0; i < 8; i++) {
            if (i) __syncthreads();       // protect LDS between tiles
            int q = cb * 8 + i;           // 0..2047: e = q>>8, kt = (q>>3)&31, nB = q&7
            int e = q >> 8, rem = q & 255, kt = rem >> 3, nB2 = rem & 7;
            tcast128(w2 + (size_t)e * H_DIM * C_DIM,
                     wt2t + ((size_t)(e * 32 + nB2 * 4) * 32 + kt) * 2048,
                     C_DIM, 32, kt, nB2 * 128, smem, t);
        }
        return;
    }

    const int lane = t & 63, w = t >> 6;
    const int ln15 = lane & 15, lg = lane >> 4;
    const int wr = w >> 1, wc = w & 1;
    const int swz = ln15 & 7;

    unsigned short* As = (unsigned short*)smem;                    // 16 KB
    unsigned short* Bs = (unsigned short*)(smem + BM * BK * 2);    // 16 KB
    int* rowtok = (int*)(smem + BM * BK * 2 + BN * BK * 2);        // 512 B

    const int ntile = plan[0] << 5;   // nmb * 32 n-blocks (each 64 h x {w1,w3})
    for (int tile = blockIdx.x; tile < ntile; tile += PGRID_UP) {
        const int mi = tile >> 5, nb = tile & 31;
        const int ent = plan[1 + mi];
        const int e = ent >> 8, m0 = (ent & 255) * BM;
        const int cnt = counts[e];

        if (t < BM) {
            int r = m0 + t;  // tail rows duplicate last valid token (benign)
            rowtok[t] = lists[e * N_TOK + (r < cnt ? r : cnt - 1)];
        }
        __syncthreads();

        const unsigned short* asrc[4];
        const unsigned short* bsrc[4];
#pragma unroll
        for (int i = 0; i < 4; i++) {   // A chunk c: row=c>>3, holds kc=(c&7)^(row&7)
            int c = i * 256 + t;
            int row = c >> 3, kc = (c & 7) ^ (row & 7);
            asrc[i] = xb + (size_t)(rowtok[row] >> 2) * C_DIM + kc * 8;
        }
#pragma unroll
        for (int i = 0; i < 4; i++) {   // B chunk: row r -> group g=r>>4
            int c = i * 256 + t;
            int r = c >> 3, kc = (c & 7) ^ (r & 7);
            int g = r >> 4;
            const unsigned short* wb = (g & 1) ? wt3t : wt1t;
            int rb = nb * 2 + (g >> 2);
            int trow = ((g >> 1) & 1) * 16 + (r & 15);
            bsrc[i] = wb + ((size_t)(e * 64 + rb) * 16) * 2048 + trow * 64 + kc * 8;
        }

        f32x4 acc[4][4];
#pragma unroll
        for (int a = 0; a < 4; a++)
#pragma unroll
            for (int b = 0; b < 4; b++) acc[a][b] = (f32x4){0.f, 0.f, 0.f, 0.f};

        KLOOP(C_DIM / BK, 4, 4, 4, wc * 64 + nt * 16 + ln15);

        // epilogue: nt pairs (0,1)=w1/w3 at p=0, (2,3) at p=1
#pragma unroll
        for (int p = 0; p < 2; p++) {
            int h = nb * 64 + (wc * 2 + p) * 16 + ln15;
            float bb1 = b1[e * H_DIM + h], bb3 = b3[e * H_DIM + h];
#pragma unroll
            for (int mt = 0; mt < 4; mt++) {
#pragma unroll
                for (int jj = 0; jj < 4; jj++) {
                    int mrow = wr * 64 + mt * 16 + lg * 4 + jj;  // C/D row=(lane>>4)*4+reg
                    float av = acc[mt][2 * p][jj] + bb1;
                    float gv = acc[mt][2 * p + 1][jj] + bb3;
                    float hv = av * gv / (1.f + __expf(-gv));    // silu(g)*a
                    int ent2 = rowtok[mrow];
                    hbuf[(size_t)((ent2 >> 2) * NSLOT + (ent2 & 3)) * H_DIM + h] = f2b(hv);
                }
            }
        }
        __syncthreads();   // protect rowtok/LDS before next tile
    }
}

// -------- expert down: 128x64 tile (R13-proven), K = H --------
__global__ __launch_bounds__(256, 4) void expert_down_kernel(
        const unsigned short* __restrict__ hbuf, const unsigned short* __restrict__ wt2t,
        const float* __restrict__ b2, const float* __restrict__ cw,
        const int* __restrict__ counts, const int* __restrict__ lists,
        const int* __restrict__ plan, unsigned short* __restrict__ outslot) {
    const int t = threadIdx.x;
    const int lane = t & 63, w = t >> 6;
    const int ln15 = lane & 15, lg = lane >> 4;
    const int wr = w >> 1, wc = w & 1;
    const int swz = ln15 & 7;

    __shared__ __align__(16) unsigned short As[BM * BK];   // 16 KB
    __shared__ __align__(16) unsigned short Bs[64 * BK];   // 8 KB
    __shared__ int rowtok[BM];

    const int ntile = plan[0] << 4;   // nmb * 16 c-blocks (N = C = 1024, BN=64)
    for (int tile = blockIdx.x; tile < ntile; tile += PGRID) {
        const int mi = tile >> 4, nb = tile & 15;
        const int ent = plan[1 + mi];
        const int e = ent >> 8, m0 = (ent & 255) * BM;
        const int cnt = counts[e];
        const int c0 = nb * 64;

        if (t < BM) {
            int r = m0 + t;
            rowtok[t] = lists[e * N_TOK + (r < cnt ? r : cnt - 1)];
        }
        __syncthreads();

        const unsigned short* asrc[4];
        const unsigned short* bsrc[2];
#pragma unroll
        for (int i = 0; i < 4; i++) {
            int c = i * 256 + t;
            int row = c >> 3, kc = (c & 7) ^ (row & 7);
            int ent2 = rowtok[row];
            asrc[i] = hbuf + (size_t)((ent2 >> 2) * NSLOT + (ent2 & 3)) * H_DIM + kc * 8;
        }
#pragma unroll
        for (int i = 0; i < 2; i++) {
            int c = i * 256 + t;
            int row = c >> 3, kc = (c & 7) ^ (row & 7);
            bsrc[i] = wt2t + (size_t)(e * 32 + nb * 2 + (row >> 5)) * 32 * 2048 +
                      (size_t)(row & 31) * 64 + kc * 8;
        }

        f32x4 acc[4][2];
#pragma unroll
        for (int a = 0; a < 4; a++)
#pragma unroll
            for (int b = 0; b < 2; b++) acc[a][b] = (f32x4){0.f, 0.f, 0.f, 0.f};

        KLOOP(H_DIM / BK, 4, 2, 2, wc * 32 + nt * 16 + ln15);

#pragma unroll
        for (int nt = 0; nt < 2; nt++) {
            int col = c0 + wc * 32 + nt * 16 + ln15;
            float bb = b2[e * C_DIM + col];
#pragma unroll
            for (int mt = 0; mt < 4; mt++) {
#pragma unroll
                for (int jj = 0; jj < 4; jj++) {
                    int mrow = wr * 64 + mt * 16 + lg * 4 + jj;
                    int ent2 = rowtok[mrow];
                    int tok = ent2 >> 2, slot = ent2 & 3;
                    float cwv = cw[tok * NE + e];
                    outslot[(size_t)(tok * NSLOT + slot) * C_DIM + col] =
                        f2b(cwv * (acc[mt][nt][jj] + bb));
                }
            }
        }
        __syncthreads();
    }
}

// -------- fused reduce (blocks 0..1023, bf16 slots) + balance loss (block 1024) ---
__global__ __launch_bounds__(256) void reduce_loss_kernel(
        const unsigned short* __restrict__ os, const float* __restrict__ cw,
        const int* __restrict__ counts, float* __restrict__ out) {
    if (blockIdx.x < 1024) {
        int i = blockIdx.x * 256 + threadIdx.x;   // over N*C/8
        int n = i >> 7;
        int c = (i & 127) * 8;
        const unsigned short* p0 = os + ((size_t)n * NSLOT + 0) * C_DIM + c;
        const unsigned short* p1 = os + ((size_t)n * NSLOT + 1) * C_DIM + c;
        const unsigned short* p2 = os + ((size_t)n * NSLOT + 2) * C_DIM + c;
        uint4 a = *(const uint4*)p0, b = *(const uint4*)p1, d = *(const uint4*)p2;
        const unsigned short* sa = (const unsigned short*)&a;
        const unsigned short* sb = (const unsigned short*)&b;
        const unsigned short* sd = (const unsigned short*)&d;
        float r[8];
#pragma unroll
        for (int j = 0; j < 8; j++) r[j] = b2f(sa[j]) + b2f(sb[j]) + b2f(sd[j]);
        float* o = out + (size_t)n * C_DIM + c;
        *(float4*)o = *(float4*)&r[0];
        *(float4*)(o + 4) = *(float4*)&r[4];
    } else if (threadIdx.x < 64) {
        int lane = threadIdx.x;
        float ss[NE];
#pragma unroll
        for (int e = 0; e < NE; e++) ss[e] = 0.f;
        for (int n = lane; n < N_TOK; n += 64) {
#pragma unroll
            for (int e = 0; e < NE; e++) ss[e] += cw[n * NE + e];
        }
#pragma unroll
        for (int e = 0; e < NE; e++) {
#pragma unroll
            for (int off = 32; off >= 1; off >>= 1) ss[e] += __shfl_xor(ss[e], off, 64);
        }
        if (lane == 0) {
            float bal = 0.f;
            const float fac = (float)NE / (3.f * (float)N_TOK * (float)N_TOK);
#pragma unroll
            for (int e = 0; e < NE; e++) bal += fac * (float)counts[e] * ss[e];
            out[(size_t)N_TOK * C_DIM] = bal;
        }
    }
}

extern "C" void kernel_launch(void* const* d_in, const int* in_sizes, int n_in,
                              void* d_out, int out_size, void* d_ws, size_t ws_size,
                              hipStream_t stream) {
    const float* x  = (const float*)d_in[0];
    const float* gw = (const float*)d_in[1];
    const float* gb = (const float*)d_in[2];
    const float* w1 = (const float*)d_in[3];
    const float* b1 = (const float*)d_in[4];
    const float* w2 = (const float*)d_in[5];
    const float* b2 = (const float*)d_in[6];
    const float* w3 = (const float*)d_in[7];
    const float* b3 = (const float*)d_in[8];
    float* out = (float*)d_out;
    char* ws = (char*)d_ws;
    int*            counts = (int*)(ws + WS_COUNTS);
    int*            plan   = (int*)(ws + WS_PLAN);
    float*          cw     = (float*)(ws + WS_CW);
    int*            route  = (int*)(ws + WS_ROUTE);
    int*            lists  = (int*)(ws + WS_LISTS);
    unsigned short* xb     = (unsigned short*)(ws + WS_XB);
    unsigned short* hbuf   = (unsigned short*)(ws + WS_HBUF);
    unsigned short* oslot  = (unsigned short*)(ws + WS_OUTSLOT);
    unsigned short* wt1t   = (unsigned short*)(ws + WS_WT1T);
    unsigned short* wt3t   = (unsigned short*)(ws + WS_WT3T);
    unsigned short* wt2t   = (unsigned short*)(ws + WS_WT2T);

    hipLaunchKernelGGL(prep_kernel, dim3(512 + 4096), dim3(256), 0, stream,
                       x, gw, gb, w1, w3, cw, xb, route, wt1t, wt3t);
    hipLaunchKernelGGL(lists_kernel, dim3(NE), dim3(64), 0, stream,
                       route, counts, lists);
    hipLaunchKernelGGL(plan_kernel, dim3(1), dim3(64), 0, stream, counts, plan);
    hipLaunchKernelGGL(expert_up_kernel, dim3(PGRID_UP + 256), dim3(256), 0, stream,
                       xb, wt1t, wt3t, b1, b3, counts, lists, plan, hbuf, w2, wt2t);
    hipLaunchKernelGGL(expert_down_kernel, dim3(PGRID), dim3(256), 0, stream,
                       hbuf, wt2t, b2, cw, counts, lists, plan, oslot);
    hipLaunchKernelGGL(reduce_loss_kernel, dim3(1025), dim3(256), 0, stream,
                       oslot, cw, counts, out);
}

// Round 18
// 186.914 us; speedup vs baseline: 1.0249x; 1.0249x over previous
//
#include <hip/hip_runtime.h>
#include <stdint.h>

#define N_TOK 2048
#define C_DIM 1024
#define H_DIM 2048
#define NE 8
#define NSLOT 3

#define BM 128
#define BN 128
#define BK 64
#define PGRID 1024

// ws layout (bytes)
#define WS_COUNTS   0
#define WS_PLAN     256
#define WS_CW       (WS_PLAN + 1024)
#define WS_ROUTE    (WS_CW + N_TOK*NE*4)
#define WS_LISTS    (WS_ROUTE + N_TOK*4)
#define WS_XB       (WS_LISTS + NE*N_TOK*4)
#define WS_HBUF     (WS_XB + (size_t)N_TOK*C_DIM*2)
#define WS_OUTSLOT  (WS_HBUF + (size_t)N_TOK*NSLOT*H_DIM*2)
#define WS_WT1T     (WS_OUTSLOT + (size_t)N_TOK*NSLOT*C_DIM*2)
#define WS_WT3T     (WS_WT1T + (size_t)NE*H_DIM*C_DIM*2)
#define WS_WT2T     (WS_WT3T + (size_t)NE*H_DIM*C_DIM*2)

typedef short bf16x8 __attribute__((ext_vector_type(8)));
typedef float f32x4 __attribute__((ext_vector_type(4)));

union FragU { bf16x8 v; uint2 u2[2]; };

__device__ __forceinline__ unsigned short f2b(float f) {
    union { float f; uint32_t u; } v; v.f = f;
    return (unsigned short)((v.u + 0x7fffu + ((v.u >> 16) & 1u)) >> 16); // RNE
}
__device__ __forceinline__ float b2f(unsigned short s) {
    union { uint32_t u; float f; } v; v.u = ((uint32_t)s) << 16; return v.f;
}

// async global->LDS, 16B per lane; lds dest is wave-uniform base + lane*16
__device__ __forceinline__ void gload16(const unsigned short* g, unsigned short* l) {
    __builtin_amdgcn_global_load_lds(
        (const __attribute__((address_space(1))) unsigned int*)g,
        (__attribute__((address_space(3))) unsigned int*)l, 16, 0, 0);
}

// ---- tcast v5: 64k x 128n fp32 -> 4 tiles [32 n][64 k] bf16 (16.9KB LDS).
__device__ __forceinline__ void tcast128(
        const float* __restrict__ src, unsigned short* __restrict__ dtile0,
        int N, int NKT, int kt, int nBase, char* lb, int t) {
    uint32_t* L = (uint32_t*)lb;                 // [64][66] u32 = 16896 B
    const int l = t & 63, w = t >> 6;
    const int half = l >> 5, ll = l & 31;
    const float* s = src + (size_t)(kt * 64) * N + nBase;
#pragma unroll 4
    for (int i = 0; i < 8; i++) {
        int k = w * 16 + i * 2 + half;
        float4 v = *(const float4*)(s + (size_t)k * N + 4 * ll);
        uint2 p;
        p.x = (uint32_t)f2b(v.x) | ((uint32_t)f2b(v.y) << 16);   // n=4ll,4ll+1
        p.y = (uint32_t)f2b(v.z) | ((uint32_t)f2b(v.w) << 16);   // n=4ll+2,4ll+3
        *(uint2*)(L + k * 66 + 2 * ll) = p;
    }
    __syncthreads();
    const int rn = t >> 3, cc = t & 7;
#pragma unroll
    for (int s2 = 0; s2 < 4; s2++) {
        int n = s2 * 32 + rn;
        int np = n >> 1, hi = (n & 1) * 16;
        uint32_t o[4];
#pragma unroll
        for (int u = 0; u < 4; u++) {            // out u32 u = k {cc*8+2u, +1}
            uint32_t a = L[(cc * 8 + 2 * u) * 66 + np];
            uint32_t b = L[(cc * 8 + 2 * u + 1) * 66 + np];
            o[u] = ((a >> hi) & 0xffffu) | (((b >> hi) & 0xffffu) << 16);
        }
        unsigned short* drow = dtile0 + (size_t)s2 * NKT * 2048 + rn * 64 + cc * 8;
        *(uint4*)drow = *(uint4*)o;
    }
}

// ---- prepass: gate (blocks 0..511, NO atomics) + w1/w3 tcast (512..4607) ----
__global__ __launch_bounds__(256) void prep_kernel(
        const float* __restrict__ x, const float* __restrict__ gw,
        const float* __restrict__ gb, const float* __restrict__ w1,
        const float* __restrict__ w3, float* __restrict__ cw,
        unsigned short* __restrict__ xb, int* __restrict__ route,
        unsigned short* __restrict__ wt1t, unsigned short* __restrict__ wt3t) {
    __shared__ __align__(16) char smem[16896];
    const int b = blockIdx.x;
    if (b >= 512) {                         // w1/w3 -> wt1t/wt3t (128-n granule)
        int bb = b - 512;
        int op = bb >> 11, r2 = bb & 2047;
        int e = r2 >> 8, rem = r2 & 255, kt = rem >> 4, nB = rem & 15;
        const float* src = (op ? w3 : w1) + (size_t)e * C_DIM * H_DIM;
        unsigned short* dst = (op ? wt3t : wt1t) +
                              ((size_t)(e * 64 + nB * 4) * 16 + kt) * 2048;
        tcast128(src, dst, H_DIM, 16, kt, nB * 128, smem, threadIdx.x);
        return;
    }
    // ---- gate: one wave per token; atomic-free ----
    int n = (b * 256 + threadIdx.x) >> 6;
    int lane = threadIdx.x & 63;
    float acc[NE];
#pragma unroll
    for (int e = 0; e < NE; e++) acc[e] = 0.f;
    for (int c = lane; c < C_DIM; c += 64) {
        float xv = x[n * C_DIM + c];
        xb[n * C_DIM + c] = f2b(xv);
        const float* g = gw + c * NE;
#pragma unroll
        for (int e = 0; e < NE; e++) acc[e] += xv * g[e];
    }
#pragma unroll
    for (int e = 0; e < NE; e++) {
#pragma unroll
        for (int off = 32; off >= 1; off >>= 1) acc[e] += __shfl_xor(acc[e], off, 64);
        acc[e] += gb[e];
    }
    float m = acc[0];
#pragma unroll
    for (int e = 1; e < NE; e++) m = fmaxf(m, acc[e]);
    float s = 0.f, sc[NE];
#pragma unroll
    for (int e = 0; e < NE; e++) { sc[e] = __expf(acc[e] - m); s += sc[e]; }
    float inv = 1.f / s;
#pragma unroll
    for (int e = 0; e < NE; e++) sc[e] *= inv;
    // top-2 of routed experts 1..7; ties -> lower index (matches lax.top_k)
    int i1 = 1; float v1 = sc[1];
#pragma unroll
    for (int e = 2; e < NE; e++) if (sc[e] > v1) { v1 = sc[e]; i1 = e; }
    int i2 = 0; float v2 = -1.f;
#pragma unroll
    for (int e = 1; e < NE; e++) if (e != i1 && sc[e] > v2) { v2 = sc[e]; i2 = e; }
    if (lane < NE) {
        float v = 0.f;
        if (lane == 0) v = sc[0];
        else if (lane == i1) v = v1;
        else if (lane == i2) v = v2;
        cw[n * NE + lane] = v;
    }
    if (lane == 0) route[n] = i1 | (i2 << 8);
}

// ---- lists+plan fused: 1 block, 8 waves (wave e = expert e), then plan ----
__global__ __launch_bounds__(512) void listsplan_kernel(
        const int* __restrict__ route, int* __restrict__ counts,
        int* __restrict__ lists, int* __restrict__ plan) {
    const int e = threadIdx.x >> 6, lane = threadIdx.x & 63;
    if (e == 0) {                             // shared expert: all tokens, slot 0
        for (int base = 0; base < N_TOK; base += 64)
            lists[base + lane] = (base + lane) * 4;
        if (lane == 0) counts[0] = N_TOK;
    } else {
        int cnt = 0;
        for (int base = 0; base < N_TOK; base += 64) {
            int r = route[base + lane];
            int i1 = r & 255, i2 = (r >> 8) & 255;
            bool mt = (i1 == e) || (i2 == e);
            int slot = (i1 == e) ? 1 : 2;
            unsigned long long mask = __ballot(mt);
            int pos = __popcll(mask & ((1ull << lane) - 1ull));
            if (mt) lists[e * N_TOK + cnt + pos] = (base + lane) * 4 + slot;
            cnt += __popcll(mask);
        }
        if (lane == 0) counts[e] = cnt;
    }
    __syncthreads();
    if (threadIdx.x == 0) {
        int p = 0;
        for (int ee = 0; ee < NE; ee++) {
            int nb = (counts[ee] + BM - 1) / BM;
            for (int m = 0; m < nb; m++) plan[1 + p++] = (ee << 8) | m;
        }
        plan[0] = p;
    }
}

// STAGE: NA A-chunks + NB B-chunks per lane (async 16B global->LDS)
#define STAGE(NA, NB, aoff, boff) do {                                    \
    _Pragma("unroll")                                                     \
    for (int i_ = 0; i_ < (NA); i_++)                                     \
        gload16(asrc[i_] + (aoff), As + (i_ * 256 + t) * 8);              \
    _Pragma("unroll")                                                     \
    for (int i_ = 0; i_ < (NB); i_++)                                     \
        gload16(bsrc[i_] + (boff), Bs + (i_ * 256 + t) * 8);              \
} while (0)

// COMPUTE: ds_read_b128 + MFMA on one 128xN x64 tile; NT = B frags per wave
#define COMPUTE(NT, BEXPR) do {                                           \
    __builtin_amdgcn_s_setprio(1);                                        \
    _Pragma("unroll")                                                     \
    for (int j_ = 0; j_ < 2; j_++) {                                      \
        FragU af[4], bf[NT];                                              \
        _Pragma("unroll")                                                 \
        for (int mt = 0; mt < 4; mt++) {                                  \
            int row = wr * 64 + mt * 16 + ln15;                           \
            int slot = (j_ * 4 + lg) ^ swz;                               \
            af[mt].v = *(const bf16x8*)(As + row * BK + slot * 8);        \
        }                                                                 \
        _Pragma("unroll")                                                 \
        for (int nt = 0; nt < (NT); nt++) {                               \
            int row = (BEXPR);                                            \
            int slot = (j_ * 4 + lg) ^ swz;                               \
            bf[nt].v = *(const bf16x8*)(Bs + row * BK + slot * 8);        \
        }                                                                 \
        _Pragma("unroll")                                                 \
        for (int mt = 0; mt < 4; mt++)                                    \
            _Pragma("unroll")                                             \
            for (int nt = 0; nt < (NT); nt++)                             \
                acc[mt][nt] = __builtin_amdgcn_mfma_f32_16x16x32_bf16(    \
                    af[mt].v, bf[nt].v, acc[mt][nt], 0, 0, 0);            \
    }                                                                     \
    __builtin_amdgcn_s_setprio(0);                                        \
} while (0)

// single-buffer K-loop: staging-BW-bound regime -> serial loop, TLP hides latency
#define KLOOP(NK, NA, NB, NT, BEXPR) do {                                 \
    for (int kt = 0; kt < (NK); kt++) {                                   \
        STAGE(NA, NB, kt * BK, kt * 2048);                                \
        asm volatile("s_waitcnt vmcnt(0)" ::: "memory");                  \
        __builtin_amdgcn_s_barrier();                                     \
        COMPUTE(NT, BEXPR);                                               \
        __builtin_amdgcn_s_barrier();                                     \
    }                                                                     \
} while (0)

// -------- expert up: 128x128 tile (R16-proven best); w2 tcast x2 in tail --------
__global__ __launch_bounds__(256, 4) void expert_up_kernel(
        const unsigned short* __restrict__ xb, const unsigned short* __restrict__ wt1t,
        const unsigned short* __restrict__ wt3t, const float* __restrict__ b1,
        const float* __restrict__ b3, const int* __restrict__ counts,
        const int* __restrict__ lists, const int* __restrict__ plan,
        unsigned short* __restrict__ hbuf, const float* __restrict__ w2,
        unsigned short* __restrict__ wt2t) {
    const int t = threadIdx.x;
    const int lane = t & 63, w = t >> 6;
    const int ln15 = lane & 15, lg = lane >> 4;
    const int wr = w >> 1, wc = w & 1;
    const int swz = ln15 & 7;

    __shared__ __align__(16) char smem[33792];
    unsigned short* As = (unsigned short*)smem;                    // 16 KB
    unsigned short* Bs = (unsigned short*)(smem + BM * BK * 2);    // 16 KB
    int* rowtok = (int*)(smem + BM * BK * 2 + BN * BK * 2);        // 512 B

    const int ntile = plan[0] << 5;   // nmb * 32 n-blocks (each 64 h x {w1,w3})
    for (int tile = blockIdx.x; tile < ntile; tile += PGRID) {
        const int mi = tile >> 5, nb = tile & 31;
        const int ent = plan[1 + mi];
        const int e = ent >> 8, m0 = (ent & 255) * BM;
        const int cnt = counts[e];

        if (t < BM) {
            int r = m0 + t;  // tail rows duplicate last valid token (benign)
            rowtok[t] = lists[e * N_TOK + (r < cnt ? r : cnt - 1)];
        }
        __syncthreads();

        const unsigned short* asrc[4];
        const unsigned short* bsrc[4];
#pragma unroll
        for (int i = 0; i < 4; i++) {   // A chunk c: row=c>>3, holds kc=(c&7)^(row&7)
            int c = i * 256 + t;
            int row = c >> 3, kc = (c & 7) ^ (row & 7);
            asrc[i] = xb + (size_t)(rowtok[row] >> 2) * C_DIM + kc * 8;
        }
#pragma unroll
        for (int i = 0; i < 4; i++) {   // B chunk: row r -> group g=r>>4
            int c = i * 256 + t;
            int r = c >> 3, kc = (c & 7) ^ (r & 7);
            int g = r >> 4;
            const unsigned short* wb = (g & 1) ? wt3t : wt1t;
            int rb = nb * 2 + (g >> 2);
            int trow = ((g >> 1) & 1) * 16 + (r & 15);
            bsrc[i] = wb + ((size_t)(e * 64 + rb) * 16) * 2048 + trow * 64 + kc * 8;
        }

        f32x4 acc[4][4];
#pragma unroll
        for (int a = 0; a < 4; a++)
#pragma unroll
            for (int b = 0; b < 4; b++) acc[a][b] = (f32x4){0.f, 0.f, 0.f, 0.f};

        KLOOP(C_DIM / BK, 4, 4, 4, wc * 64 + nt * 16 + ln15);

        // epilogue: nt pairs (0,1)=w1/w3 at p=0, (2,3) at p=1
#pragma unroll
        for (int p = 0; p < 2; p++) {
            int h = nb * 64 + (wc * 2 + p) * 16 + ln15;
            float bb1 = b1[e * H_DIM + h], bb3 = b3[e * H_DIM + h];
#pragma unroll
            for (int mt = 0; mt < 4; mt++) {
#pragma unroll
                for (int jj = 0; jj < 4; jj++) {
                    int mrow = wr * 64 + mt * 16 + lg * 4 + jj;  // C/D row=(lane>>4)*4+reg
                    float av = acc[mt][2 * p][jj] + bb1;
                    float gv = acc[mt][2 * p + 1][jj] + bb3;
                    float hv = av * gv / (1.f + __expf(-gv));    // silu(g)*a
                    int ent2 = rowtok[mrow];
                    hbuf[(size_t)((ent2 >> 2) * NSLOT + (ent2 & 3)) * H_DIM + h] = f2b(hv);
                }
            }
        }
        __syncthreads();   // protect rowtok/LDS before next tile
    }

    // ---- tail: two w2 tcast tiles per block (2048 tiles total) ----
#pragma unroll 1
    for (int q = 0; q < 2; q++) {
        if (q) __syncthreads();   // protect LDS between the two casts
        int bb = blockIdx.x * 2 + q;
        int e = bb >> 8, rem = bb & 255, kt = rem >> 3, nB2 = rem & 7;
        tcast128(w2 + (size_t)e * H_DIM * C_DIM,
                 wt2t + ((size_t)(e * 32 + nB2 * 4) * 32 + kt) * 2048,
                 C_DIM, 32, kt, nB2 * 128, smem, t);
    }
}

// -------- expert down: 128x64 tile (R16-proven), K = H --------
__global__ __launch_bounds__(256, 4) void expert_down_kernel(
        const unsigned short* __restrict__ hbuf, const unsigned short* __restrict__ wt2t,
        const float* __restrict__ b2, const float* __restrict__ cw,
        const int* __restrict__ counts, const int* __restrict__ lists,
        const int* __restrict__ plan, unsigned short* __restrict__ outslot) {
    const int t = threadIdx.x;
    const int lane = t & 63, w = t >> 6;
    const int ln15 = lane & 15, lg = lane >> 4;
    const int wr = w >> 1, wc = w & 1;
    const int swz = ln15 & 7;

    __shared__ __align__(16) unsigned short As[BM * BK];   // 16 KB
    __shared__ __align__(16) unsigned short Bs[64 * BK];   // 8 KB
    __shared__ int rowtok[BM];

    const int ntile = plan[0] << 4;   // nmb * 16 c-blocks (N = C = 1024, BN=64)
    for (int tile = blockIdx.x; tile < ntile; tile += PGRID) {
        const int mi = tile >> 4, nb = tile & 15;
        const int ent = plan[1 + mi];
        const int e = ent >> 8, m0 = (ent & 255) * BM;
        const int cnt = counts[e];
        const int c0 = nb * 64;

        if (t < BM) {
            int r = m0 + t;
            rowtok[t] = lists[e * N_TOK + (r < cnt ? r : cnt - 1)];
        }
        __syncthreads();

        const unsigned short* asrc[4];
        const unsigned short* bsrc[2];
#pragma unroll
        for (int i = 0; i < 4; i++) {
            int c = i * 256 + t;
            int row = c >> 3, kc = (c & 7) ^ (row & 7);
            int ent2 = rowtok[row];
            asrc[i] = hbuf + (size_t)((ent2 >> 2) * NSLOT + (ent2 & 3)) * H_DIM + kc * 8;
        }
#pragma unroll
        for (int i = 0; i < 2; i++) {
            int c = i * 256 + t;
            int row = c >> 3, kc = (c & 7) ^ (row & 7);
            bsrc[i] = wt2t + (size_t)(e * 32 + nb * 2 + (row >> 5)) * 32 * 2048 +
                      (size_t)(row & 31) * 64 + kc * 8;
        }

        f32x4 acc[4][2];
#pragma unroll
        for (int a = 0; a < 4; a++)
#pragma unroll
            for (int b = 0; b < 2; b++) acc[a][b] = (f32x4){0.f, 0.f, 0.f, 0.f};

        KLOOP(H_DIM / BK, 4, 2, 2, wc * 32 + nt * 16 + ln15);

#pragma unroll
        for (int nt = 0; nt < 2; nt++) {
            int col = c0 + wc * 32 + nt * 16 + ln15;
            float bb = b2[e * C_DIM + col];
#pragma unroll
            for (int mt = 0; mt < 4; mt++) {
#pragma unroll
                for (int jj = 0; jj < 4; jj++) {
                    int mrow = wr * 64 + mt * 16 + lg * 4 + jj;
                    int ent2 = rowtok[mrow];
                    int tok = ent2 >> 2, slot = ent2 & 3;
                    float cwv = cw[tok * NE + e];
                    outslot[(size_t)(tok * NSLOT + slot) * C_DIM + col] =
                        f2b(cwv * (acc[mt][nt][jj] + bb));
                }
            }
        }
        __syncthreads();
    }
}

// -------- fused reduce (blocks 0..1023, bf16 slots) + balance loss (block 1024) ---
__global__ __launch_bounds__(256) void reduce_loss_kernel(
        const unsigned short* __restrict__ os, const float* __restrict__ cw,
        const int* __restrict__ counts, float* __restrict__ out) {
    if (blockIdx.x < 1024) {
        int i = blockIdx.x * 256 + threadIdx.x;   // over N*C/8
        int n = i >> 7;
        int c = (i & 127) * 8;
        const unsigned short* p0 = os + ((size_t)n * NSLOT + 0) * C_DIM + c;
        const unsigned short* p1 = os + ((size_t)n * NSLOT + 1) * C_DIM + c;
        const unsigned short* p2 = os + ((size_t)n * NSLOT + 2) * C_DIM + c;
        uint4 a = *(const uint4*)p0, b = *(const uint4*)p1, d = *(const uint4*)p2;
        const unsigned short* sa = (const unsigned short*)&a;
        const unsigned short* sb = (const unsigned short*)&b;
        const unsigned short* sd = (const unsigned short*)&d;
        float r[8];
#pragma unroll
        for (int j = 0; j < 8; j++) r[j] = b2f(sa[j]) + b2f(sb[j]) + b2f(sd[j]);
        float* o = out + (size_t)n * C_DIM + c;
        *(float4*)o = *(float4*)&r[0];
        *(float4*)(o + 4) = *(float4*)&r[4];
    } else if (threadIdx.x < 64) {
        int lane = threadIdx.x;
        float ss[NE];
#pragma unroll
        for (int e = 0; e < NE; e++) ss[e] = 0.f;
        for (int n = lane; n < N_TOK; n += 64) {
#pragma unroll
            for (int e = 0; e < NE; e++) ss[e] += cw[n * NE + e];
        }
#pragma unroll
        for (int e = 0; e < NE; e++) {
#pragma unroll
            for (int off = 32; off >= 1; off >>= 1) ss[e] += __shfl_xor(ss[e], off, 64);
        }
        if (lane == 0) {
            float bal = 0.f;
            const float fac = (float)NE / (3.f * (float)N_TOK * (float)N_TOK);
#pragma unroll
            for (int e = 0; e < NE; e++) bal += fac * (float)counts[e] * ss[e];
            out[(size_t)N_TOK * C_DIM] = bal;
        }
    }
}

extern "C" void kernel_launch(void* const* d_in, const int* in_sizes, int n_in,
                              void* d_out, int out_size, void* d_ws, size_t ws_size,
                              hipStream_t stream) {
    const float* x  = (const float*)d_in[0];
    const float* gw = (const float*)d_in[1];
    const float* gb = (const float*)d_in[2];
    const float* w1 = (const float*)d_in[3];
    const float* b1 = (const float*)d_in[4];
    const float* w2 = (const float*)d_in[5];
    const float* b2 = (const float*)d_in[6];
    const float* w3 = (const float*)d_in[7];
    const float* b3 = (const float*)d_in[8];
    float* out = (float*)d_out;
    char* ws = (char*)d_ws;
    int*            counts = (int*)(ws + WS_COUNTS);
    int*            plan   = (int*)(ws + WS_PLAN);
    float*          cw     = (float*)(ws + WS_CW);
    int*            route  = (int*)(ws + WS_ROUTE);
    int*            lists  = (int*)(ws + WS_LISTS);
    unsigned short* xb     = (unsigned short*)(ws + WS_XB);
    unsigned short* hbuf   = (unsigned short*)(ws + WS_HBUF);
    unsigned short* oslot  = (unsigned short*)(ws + WS_OUTSLOT);
    unsigned short* wt1t   = (unsigned short*)(ws + WS_WT1T);
    unsigned short* wt3t   = (unsigned short*)(ws + WS_WT3T);
    unsigned short* wt2t   = (unsigned short*)(ws + WS_WT2T);

    hipLaunchKernelGGL(prep_kernel, dim3(512 + 4096), dim3(256), 0, stream,
                       x, gw, gb, w1, w3, cw, xb, route, wt1t, wt3t);
    hipLaunchKernelGGL(listsplan_kernel, dim3(1), dim3(512), 0, stream,
                       route, counts, lists, plan);
    hipLaunchKernelGGL(expert_up_kernel, dim3(PGRID), dim3(256), 0, stream,
                       xb, wt1t, wt3t, b1, b3, counts, lists, plan, hbuf, w2, wt2t);
    hipLaunchKernelGGL(expert_down_kernel, dim3(PGRID), dim3(256), 0, stream,
                       hbuf, wt2t, b2, cw, counts, lists, plan, oslot);
    hipLaunchKernelGGL(reduce_loss_kernel, dim3(1025), dim3(256), 0, stream,
                       oslot, cw, counts, out);
}